// Round 8
// baseline (91.335 us; speedup 1.0000x reference)
//
#include <hip/hip_runtime.h>
#include <math.h>

// TopologicalValuePolicy — MI355X, R7: 2 boards/block, 4 barriers per block.
// conv[p][v] = 6*(Wv - Cv) - 5*(W0+W1+W2) over 5-windows along 4 line
// orientations; e0 = l0-5(l1+l2), e1 = l1-5(l0+l2):
//   a_v = (5-sum of e_v along oriented line) - 6*C_v
// All LDS field-paired as float2 (x=cur, y=oth). Threads [0,320) = board A,
// [320,640) = board B (waves board-pure). Barrier diet: zeroing folded into
// staging; reductions use write-partials -> barrier -> all-thread broadcast
// combine (no tid0 serial round). 2 barriers per board vs 7 in R3-R6 —
// attacks the measured ~35us stall plateau that instruction-count cuts
// (R3/R5/R6 all neutral) could not move.

__device__ __forceinline__ float fpow(float x, float e) {
    float r = __builtin_amdgcn_exp2f(e * __builtin_amdgcn_logf(x));
    return (x > 0.f) ? r : 0.f;
}
__device__ __forceinline__ float fexp(float x) {
    return __builtin_amdgcn_exp2f(x * 1.44269504088896f);
}

// float2-unit offsets within one board's slab
#define F2_E   0        // 27x27 zero-padded e-field pairs
#define F2_C   729      // 289 center pairs (6*l0, 6*l1)
#define F2_GH  1018     // [17][21]
#define F2_GV  1375     // [17][21]
#define F2_GD  1732     // [33][22]
#define F2_GA  2458     // [33][21]
#define F2_SLAB 3152    // per-board slab size
#define F2_DUMMY 6304   // shared write sink
#define F2_TOTAL 6305   // 50,440 B -> 3 blocks/CU

__global__ __launch_bounds__(640) void topo_policy_value(
    const float* __restrict__ state,
    float* __restrict__ probs,
    float* __restrict__ value,
    int nb)
{
    __shared__ float2 l2[F2_TOTAL];
    __shared__ float rmax[10], rdif[10], rsum[10];

    const int tid = threadIdx.x;
    const int s   = tid >= 320;          // board slot within block
    const int w   = tid - (s ? 320 : 0); // 0..319 within slot
    const int sb  = blockIdx.x * 2 + s;  // global board index
    const bool vboard = sb < nb;
    const int base = s ? F2_SLAB : 0;

    // ---- stage (zero + e-pair + centers in one pass) ----
    const float* src = state + (size_t)sb * (19 * 19 * 3);
    #pragma unroll
    for (int it = 0; it < 3; ++it) {
        int j = w + it * 320;
        if (j < 729) {
            int py = j / 27, px = j - py * 27;
            int r = py - 4, c = px - 4;
            bool in = vboard && (unsigned)r < 19u && (unsigned)c < 19u;
            float l0 = 0.f, l1 = 0.f, lv2 = 0.f;
            if (in) {
                int o = 3 * (r * 19 + c);
                l0 = src[o]; l1 = src[o + 1]; lv2 = src[o + 2];
            }
            float e0 = fmaf(-5.f, l1 + lv2, l0);
            float e1 = fmaf(-5.f, l0 + lv2, l1);
            l2[base + F2_E + j] = make_float2(e0, e1);
            if (r >= 1 && r <= 17 && c >= 1 && c <= 17) {
                l2[base + F2_C + (r - 1) * 17 + (c - 1)] =
                    make_float2(6.f * l0, 6.f * l1);
            }
        }
    }
    __syncthreads();

    // ---- oriented sliding 5-sums: 100 workers per board ----
    if (w < 100) {
        int t = w, L;
        int gb, step, outp, cnt;
        if (t < 17) {                       // horizontal
            L = t;
            gb = (L + 5) * 27 + 1; step = 1;
            outp = F2_GH + L * 21; cnt = 21;
        } else if (t < 34) {                // vertical
            L = t - 17;
            gb = 27 + (L + 5); step = 27;
            outp = F2_GV + L * 21; cnt = 21;
        } else if (t < 67) {                // diagonal, delta = L-16
            L = t - 34;
            int d = L - 16;
            int j0 = (d < 0) ? -d : 0;
            gb = (j0 + 1 + d) * 27 + (j0 + 1); step = 28;
            outp = F2_GD + L * 22 + j0;
            cnt = 21 - ((d < 0) ? -d : d);
        } else {                            // anti-diagonal, sigma = L
            L = t - 67;
            int k0 = (L > 16) ? (L - 16) : 0;
            int k1 = (L + 4 < 20) ? (L + 4) : 20;
            gb = 26 * k0 + 36 + L; step = 26;
            outp = F2_GA + L * 21 + k0;
            cnt = k1 - k0 + 1;
        }
        gb += base; outp += base;
        float2 buf[5];
        #pragma unroll
        for (int i = 0; i < 5; ++i) buf[i] = l2[gb + i * step];
        float sx = buf[0].x + buf[1].x + buf[2].x + buf[3].x + buf[4].x;
        float sy = buf[0].y + buf[1].y + buf[2].y + buf[3].y + buf[4].y;
        #pragma unroll
        for (int i = 0; i < 21; ++i) {
            int dst = (i < cnt) ? (outp + i) : F2_DUMMY;
            l2[dst] = make_float2(sx, sy);
            float2 nc = l2[gb + (i + 5) * step];   // +cell(i+5) -cell(i)
            float2 oc = buf[i % 5];
            sx += nc.x - oc.x;
            sy += nc.y - oc.y;
            buf[i % 5] = nc;
        }
    }
    __syncthreads();

    // ---- main compute: one position per thread (289 of 320 per board) ----
    const bool act = w < 289;
    float fcur = 0.f, foth = 0.f;
    if (act) {
        const int y = w / 17;
        const int x = w - y * 17;
        const float2 h = l2[base + F2_C + w];

        const int bh = base + F2_GH + y * 21 + x;
        const int bv = base + F2_GV + x * 21 + y;
        const int bd = base + F2_GD + (y - x + 16) * 22 + x;
        const int ba = base + F2_GA + (y + x) * 21 + y;

        float sd0 = 0.f, sd1 = 0.f;
        #define ORIENT(B)                                             \
        {                                                             \
            float t0 = 0.f, t1 = 0.f;                                 \
            _Pragma("unroll")                                         \
            for (int i = 0; i < 5; ++i) {                             \
                float2 wv = l2[(B) + i];                              \
                float a0 = fmaxf(wv.x - h.x, 0.f);                    \
                float a1 = fmaxf(wv.y - h.y, 0.f);                    \
                float q0 = a0 * a0, q1 = a1 * a1;                     \
                float m0 = q0 * q0, m1 = q1 * q1;                     \
                t0 = fmaf(m0, q0, t0); t1 = fmaf(m1, q1, t1);         \
            }                                                         \
            sd0 += fpow(t0, 5.0f / 6.0f);                             \
            sd1 += fpow(t1, 5.0f / 6.0f);                             \
        }
        ORIENT(bh)
        ORIENT(bv)
        ORIENT(bd)
        ORIENT(ba)
        #undef ORIENT

        fcur = fpow(sd0, 0.2f);
        foth = fpow(sd1, 0.2f);
    }

    // ---- per-board reductions (waves are board-pure) ----
    const float g = act ? 2.f * (fcur + foth) : -3.0e38f;
    float lmax = g;
    float ldif = fcur - foth;   // 0 when inactive
    #pragma unroll
    for (int off = 32; off > 0; off >>= 1) {
        lmax = fmaxf(lmax, __shfl_down(lmax, off, 64));
        ldif += __shfl_down(ldif, off, 64);
    }
    const int wv_id = tid >> 6;          // 0..9, board = wv_id/5
    if ((tid & 63) == 0) { rmax[wv_id] = lmax; rdif[wv_id] = ldif; }
    __syncthreads();

    const int rb = s * 5;
    float M = rmax[rb];
    #pragma unroll
    for (int k = 1; k < 5; ++k) M = fmaxf(M, rmax[rb + k]);

    const float e = act ? fexp(g - M) : 0.f;
    float lsum = e;
    #pragma unroll
    for (int off = 32; off > 0; off >>= 1) lsum += __shfl_down(lsum, off, 64);
    if ((tid & 63) == 0) rsum[wv_id] = lsum;
    __syncthreads();

    float S = rsum[rb] + rsum[rb + 1] + rsum[rb + 2] + rsum[rb + 3] + rsum[rb + 4];
    const float invS = 1.0f / S;
    if (vboard && act) probs[(size_t)sb * 289 + w] = e * invS;
    if (vboard && w == 0) {
        float D = rdif[rb] + rdif[rb + 1] + rdif[rb + 2] + rdif[rb + 3] + rdif[rb + 4];
        value[sb] = tanhf(D * (0.2f / 32.0f));
    }
}

extern "C" void kernel_launch(void* const* d_in, const int* in_sizes, int n_in,
                              void* d_out, int out_size, void* d_ws, size_t ws_size,
                              hipStream_t stream) {
    const float* state = (const float*)d_in[0];
    const int nb = in_sizes[0] / (19 * 19 * 3);   // 4096
    float* probs = (float*)d_out;                  // (nb, 289)
    float* value = probs + (size_t)nb * 289;       // (nb,)
    const int grid = (nb + 1) / 2;
    topo_policy_value<<<dim3(grid), dim3(640), 0, stream>>>(state, probs, value, nb);
}

// Round 9
// 84.839 us; speedup vs baseline: 1.0766x; 1.0766x over previous
//
#include <hip/hip_runtime.h>
#include <math.h>

// TopologicalValuePolicy — MI355X, R8: wave-per-board, ZERO barriers.
// conv[p][v] over 5-windows along 4 line orientations; with
// e0 = l0-5(l1+l2), e1 = l1-5(l0+l2):  a_v = (5-window-sum of e_v) - 6*C_v.
// One 64-lane wave owns one board: stage zero-padded 27x27 E-plane (float2,
// x=cur,y=oth) + 289 center pairs into a private 8KB LDS slab; one
// s_waitcnt(0)+wave_barrier; each lane computes positions lane+64k (k<5)
// straight from E (windows are order-invariant under the sum over p, so
// slide 4..8 -> 0..4); softmax + value via __shfl_xor butterflies only.
// Rationale: R3/R5/R6/R7 (work cuts, barrier cuts) all neutral at ~35-40us
// vs ~8us issue math -> the stall is block-wide lockstep coupling. This
// removes every block-level sync; waves slide independently (20/CU).

__device__ __forceinline__ float fpow(float x, float e) {
    float r = __builtin_amdgcn_exp2f(e * __builtin_amdgcn_logf(x));
    return (x > 0.f) ? r : 0.f;
}
__device__ __forceinline__ float fexp(float x) {
    return __builtin_amdgcn_exp2f(x * 1.44269504088896f);
}

#define SLAB 1024          // float2 per board: 729 E + 289 C + pad
#define C_OFF 729

__global__ __launch_bounds__(256) void topo_policy_value(
    const float* __restrict__ state,
    float* __restrict__ probs,
    float* __restrict__ value,
    int nb)
{
    __shared__ float2 l2[4 * SLAB];

    const int tid  = threadIdx.x;
    const int wv   = tid >> 6;           // wave in block 0..3
    const int lane = tid & 63;
    const int b    = blockIdx.x * 4 + wv;
    if (b >= nb) return;                  // wave-uniform; no later block sync
    float2* s2 = l2 + wv * SLAB;

    const float* src = state + (size_t)b * (19 * 19 * 3);

    // ---- stage E plane (zero-padded 27x27) ----
    #pragma unroll
    for (int it = 0; it < 12; ++it) {
        int j = lane + it * 64;
        if (j < 729) {
            int py = j / 27, px = j - py * 27;
            int r = py - 4, c = px - 4;
            float l0 = 0.f, l1 = 0.f, lv = 0.f;
            if ((unsigned)r < 19u && (unsigned)c < 19u) {
                int o = 3 * (r * 19 + c);
                l0 = src[o]; l1 = src[o + 1]; lv = src[o + 2];
            }
            s2[j] = make_float2(fmaf(-5.f, l1 + lv, l0),
                                fmaf(-5.f, l0 + lv, l1));
        }
    }
    // ---- stage center pairs (6*l0, 6*l1) ----
    #pragma unroll
    for (int it = 0; it < 5; ++it) {
        int j = lane + it * 64;
        if (j < 289) {
            int y = j / 17, x = j - y * 17;
            int o = 3 * ((y + 1) * 19 + (x + 1));
            s2[C_OFF + j] = make_float2(6.f * src[o], 6.f * src[o + 1]);
        }
    }
    // wave-synchronous fence: drain LDS writes, block compiler reordering
    __builtin_amdgcn_s_waitcnt(0);
    __builtin_amdgcn_wave_barrier();

    // ---- per-lane positions: p = lane + 64k ----
    float g[5], es[5];
    float dif = 0.f;
    #pragma unroll
    for (int k = 0; k < 5; ++k) {
        int p = lane + 64 * k;
        float gk = -3.0e38f;
        if (p < 289) {
            int y = p / 17, x = p - y * 17;
            float2 h = s2[C_OFF + p];
            // orientation line starts (i=0) and steps in the padded plane
            int c0 = (y + 5) * 27 + (x + 1);   // H, step 1
            int c1 = (y + 1) * 27 + (x + 5);   // V, step 27
            int c2 = (y + 1) * 27 + (x + 1);   // D, step 28
            int c3 = (y + 1) * 27 + (x + 9);   // A, step 26
            float sd0 = 0.f, sd1 = 0.f;
            #define ORIENT(BASE, STEP)                                      \
            {                                                               \
                float2 e[9];                                                \
                _Pragma("unroll")                                           \
                for (int i = 0; i < 9; ++i) e[i] = s2[(BASE) + i * (STEP)]; \
                float wx = e[4].x + e[5].x + e[6].x + e[7].x + e[8].x;      \
                float wy = e[4].y + e[5].y + e[6].y + e[7].y + e[8].y;      \
                float t0 = 0.f, t1 = 0.f;                                   \
                _Pragma("unroll")                                           \
                for (int pp = 0; pp < 5; ++pp) {                            \
                    float a0 = fmaxf(wx - h.x, 0.f);                        \
                    float a1 = fmaxf(wy - h.y, 0.f);                        \
                    float q0 = a0 * a0, q1 = a1 * a1;                       \
                    t0 = fmaf(q0 * q0, q0, t0);                             \
                    t1 = fmaf(q1 * q1, q1, t1);                             \
                    if (pp < 4) {                                           \
                        wx += e[3 - pp].x - e[8 - pp].x;                    \
                        wy += e[3 - pp].y - e[8 - pp].y;                    \
                    }                                                       \
                }                                                           \
                sd0 += fpow(t0, 5.0f / 6.0f);                               \
                sd1 += fpow(t1, 5.0f / 6.0f);                               \
            }
            ORIENT(c0, 1)
            ORIENT(c1, 27)
            ORIENT(c2, 28)
            ORIENT(c3, 26)
            #undef ORIENT
            float fc = fpow(sd0, 0.2f);
            float fo = fpow(sd1, 0.2f);
            gk = 2.f * (fc + fo);
            dif += fc - fo;
        }
        g[k] = gk;
    }

    // ---- wave-only reductions (no LDS, no barriers) ----
    float M = fmaxf(fmaxf(fmaxf(g[0], g[1]), fmaxf(g[2], g[3])), g[4]);
    #pragma unroll
    for (int off = 32; off > 0; off >>= 1)
        M = fmaxf(M, __shfl_xor(M, off, 64));

    float S = 0.f;
    #pragma unroll
    for (int k = 0; k < 5; ++k) {
        es[k] = (g[k] > -1.0e38f) ? fexp(g[k] - M) : 0.f;
        S += es[k];
    }
    #pragma unroll
    for (int off = 32; off > 0; off >>= 1) S += __shfl_xor(S, off, 64);
    #pragma unroll
    for (int off = 32; off > 0; off >>= 1) dif += __shfl_xor(dif, off, 64);

    const float invS = __builtin_amdgcn_rcpf(S);
    float* pout = probs + (size_t)b * 289;
    #pragma unroll
    for (int k = 0; k < 5; ++k) {
        int p = lane + 64 * k;
        if (p < 289) pout[p] = es[k] * invS;
    }
    if (lane == 0) {
        float z = dif * (0.2f / 32.0f);
        float t = __builtin_amdgcn_exp2f(z * (2.0f * 1.44269504088896f));
        value[b] = (t - 1.f) * __builtin_amdgcn_rcpf(t + 1.f);  // tanh(z)
    }
}

extern "C" void kernel_launch(void* const* d_in, const int* in_sizes, int n_in,
                              void* d_out, int out_size, void* d_ws, size_t ws_size,
                              hipStream_t stream) {
    const float* state = (const float*)d_in[0];
    const int nb = in_sizes[0] / (19 * 19 * 3);   // 4096
    float* probs = (float*)d_out;                  // (nb, 289)
    float* value = probs + (size_t)nb * 289;       // (nb,)
    const int grid = (nb + 3) / 4;
    topo_policy_value<<<dim3(grid), dim3(256), 0, stream>>>(state, probs, value, nb);
}